// Round 1
// baseline (97.323 us; speedup 1.0000x reference)
//
#include <hip/hip_runtime.h>
#include <hip/hip_bf16.h>

// Problem: B=8, CIN=8, COUT=8, NX=NT=512, M1=M2=4.
// xs = x[:,:,::2,::2] (256x256); rfft2; keep modes (kx in {0..3,252..255}) x (kw in {0..3});
// mix over cin with w1 (rows 0..3) / w2 (rows 252..255); evaluate
// out[b,o,z,i] = Re( sum_{m,kw} c[b,o,m,kw] e^{2pi i (m z + kw i)/512} ) / 65536.

#define PI2 6.283185307179586f

// ---- K1: DFT over t (4 modes) per (b,cin,y) row. One wave per row. ----
__global__ void k_dft_t(const float* __restrict__ x, float2* __restrict__ partial) {
    int gid  = blockIdx.x * blockDim.x + threadIdx.x;
    int wid  = gid >> 6;          // row index in [0, 64*256)
    int lane = gid & 63;
    int bc = wid >> 8;            // b*8+cin
    int y  = wid & 255;
    const float* row = x + ((size_t)bc * 512 + (size_t)(2 * y)) * 512;

    float ar[4] = {0.f, 0.f, 0.f, 0.f};
    float ai[4] = {0.f, 0.f, 0.f, 0.f};
#pragma unroll
    for (int k = 0; k < 4; ++k) {
        int t = lane + 64 * k;
        float v = row[2 * t];
        float ang = (PI2 / 256.0f) * (float)t;
        float s, c;
        sincosf(ang, &s, &c);
        float er = c, ei = -s;        // e^{-i*2pi*t/256}
        float pr = 1.f, pim = 0.f;    // (e^{-i ang})^kw, kw=0
#pragma unroll
        for (int kw = 0; kw < 4; ++kw) {
            ar[kw] += v * pr;
            ai[kw] += v * pim;
            float npr = pr * er - pim * ei;
            float npi = pr * ei + pim * er;
            pr = npr; pim = npi;
        }
    }
    // wave tree-reduce
#pragma unroll
    for (int m = 1; m < 64; m <<= 1) {
#pragma unroll
        for (int kw = 0; kw < 4; ++kw) {
            ar[kw] += __shfl_xor(ar[kw], m, 64);
            ai[kw] += __shfl_xor(ai[kw], m, 64);
        }
    }
    if (lane == 0) {
#pragma unroll
        for (int kw = 0; kw < 4; ++kw)
            partial[wid * 4 + kw] = make_float2(ar[kw], ai[kw]);
    }
}

// ---- K2: DFT over y (8 modes m in {0..3,-4..-1}). One thread per output. ----
__global__ void k_dft_y(const float2* __restrict__ partial, float2* __restrict__ FWc) {
    int tid = blockIdx.x * blockDim.x + threadIdx.x;  // 2048
    if (tid >= 2048) return;
    int kw = tid & 3, midx = (tid >> 2) & 7, bc = tid >> 5;
    float m = (midx < 4) ? (float)midx : (float)(midx - 8);
    float2 acc = make_float2(0.f, 0.f);
    for (int y = 0; y < 256; ++y) {
        float2 p = partial[(bc * 256 + y) * 4 + kw];
        float ang = (PI2 / 256.0f) * m * (float)y;
        float s, c;
        sincosf(ang, &s, &c);
        // p * e^{-i ang} = p * (c - i s)
        acc.x += p.x * c + p.y * s;
        acc.y += p.y * c - p.x * s;
    }
    FWc[tid] = acc;
}

// ---- K3: channel mix with weights. One thread per (b,o,midx,kw). ----
__global__ void k_mix(const float2* __restrict__ FWc, const float* __restrict__ w1,
                      const float* __restrict__ w2, float2* __restrict__ c2) {
    int tid = blockIdx.x * blockDim.x + threadIdx.x;  // 2048
    if (tid >= 2048) return;
    int kw = tid & 3, midx = (tid >> 2) & 7, o = (tid >> 5) & 7, b = tid >> 8;
    const float* w = (midx < 4) ? w1 : w2;
    int mx = midx & 3;
    float2 acc = make_float2(0.f, 0.f);
#pragma unroll
    for (int ci = 0; ci < 8; ++ci) {
        float2 f = FWc[((b * 8 + ci) * 8 + midx) * 4 + kw];
        const float* wp = w + ((((ci * 8 + o) * 4 + mx) * 4 + kw) * 2);
        float wr = wp[0], wi = wp[1];
        acc.x += f.x * wr - f.y * wi;
        acc.y += f.x * wi + f.y * wr;
    }
    c2[tid] = acc;
}

// ---- K4: h[b,o,z,kw] = sum_m c2 * e^{+2pi i m z/512}. One thread per output. ----
__global__ void k_h(const float2* __restrict__ c2, float2* __restrict__ h) {
    int tid = blockIdx.x * blockDim.x + threadIdx.x;  // 131072
    int kw = tid & 3, z = (tid >> 2) & 511, bo = tid >> 11;
    float2 acc = make_float2(0.f, 0.f);
#pragma unroll
    for (int midx = 0; midx < 8; ++midx) {
        float m = (midx < 4) ? (float)midx : (float)(midx - 8);
        float ang = (PI2 / 512.0f) * m * (float)z;
        float s, c;
        sincosf(ang, &s, &c);
        float2 cc = c2[(bo * 8 + midx) * 4 + kw];
        acc.x += cc.x * c - cc.y * s;
        acc.y += cc.x * s + cc.y * c;
    }
    h[tid] = acc;
}

// ---- K5: evaluate over i, write output. One wave per (b,o,z) row. ----
__global__ void k_eval(const float2* __restrict__ h, float* __restrict__ out) {
    int gid  = blockIdx.x * blockDim.x + threadIdx.x;
    int wid  = gid >> 6;          // row in [0, 32768)
    int lane = gid & 63;
    const float2* hr = h + (size_t)wid * 4;
    float2 h0 = hr[0], h1 = hr[1], h2 = hr[2], h3 = hr[3];
    float* orow = out + (size_t)wid * 512;
    const float inv = 1.0f / 65536.0f;
#pragma unroll
    for (int half = 0; half < 2; ++half) {
        int i0 = half * 256 + lane * 4;
        float4 r;
        float* rp = &r.x;
#pragma unroll
        for (int j = 0; j < 4; ++j) {
            int i = i0 + j;
            float ang = (PI2 / 512.0f) * (float)i;
            float s1, c1;
            sincosf(ang, &s1, &c1);
            float c2_ = c1 * c1 - s1 * s1, s2_ = 2.f * c1 * s1;
            float c3_ = c2_ * c1 - s2_ * s1, s3_ = s2_ * c1 + c2_ * s1;
            float v = h0.x
                    + h1.x * c1 - h1.y * s1
                    + h2.x * c2_ - h2.y * s2_
                    + h3.x * c3_ - h3.y * s3_;
            rp[j] = v * inv;
        }
        *(float4*)(orow + i0) = r;
    }
}

extern "C" void kernel_launch(void* const* d_in, const int* in_sizes, int n_in,
                              void* d_out, int out_size, void* d_ws, size_t ws_size,
                              hipStream_t stream) {
    const float* x  = (const float*)d_in[0];
    const float* w1 = (const float*)d_in[3];
    const float* w2 = (const float*)d_in[4];
    float* out = (float*)d_out;

    // workspace layout (float2 units)
    float2* partial = (float2*)d_ws;            // 64*256*4   = 65536
    float2* FWc     = partial + 65536;          // 64*8*4     = 2048
    float2* c2      = FWc + 2048;               // 64*8*4     = 2048
    float2* h       = c2 + 2048;                // 64*512*4   = 131072
    // total 201,728 float2 = ~1.6 MB

    // K1: 16384 waves = 1,048,576 threads
    k_dft_t<<<4096, 256, 0, stream>>>(x, partial);
    // K2: 2048 threads
    k_dft_y<<<8, 256, 0, stream>>>(partial, FWc);
    // K3: 2048 threads
    k_mix<<<8, 256, 0, stream>>>(FWc, w1, w2, c2);
    // K4: 131072 threads
    k_h<<<512, 256, 0, stream>>>(c2, h);
    // K5: 32768 waves = 2,097,152 threads
    k_eval<<<8192, 256, 0, stream>>>(h, out);
}

// Round 2
// 42.064 us; speedup vs baseline: 2.3137x; 2.3137x over previous
//
#include <hip/hip_runtime.h>
#include <hip/hip_bf16.h>

// Problem: B=8, CIN=8, COUT=8, NX=NT=512, M1=M2=4.
// xs = x[:,:,::2,::2] (256x256); rfft2; keep modes (kx in {0..3,252..255}) x (kw in {0..3});
// mix over cin with w1 (rows 0..3) / w2 (rows 252..255); evaluate
// out[b,o,z,i] = Re( sum_{m,kw} c[b,o,m,kw] e^{2pi i (m z + kw i)/512} ) / 65536.

#define PI2 6.283185307179586f

// ---- K1: DFT over t (4 modes) per (b,cin,y) row. One wave per row. ----
__global__ void k_dft_t(const float* __restrict__ x, float2* __restrict__ partial) {
    int gid  = blockIdx.x * blockDim.x + threadIdx.x;
    int wid  = gid >> 6;          // row index in [0, 64*256)
    int lane = gid & 63;
    int bc = wid >> 8;            // b*8+cin
    int y  = wid & 255;
    const float* row = x + ((size_t)bc * 512 + (size_t)(2 * y)) * 512;

    float ar[4] = {0.f, 0.f, 0.f, 0.f};
    float ai[4] = {0.f, 0.f, 0.f, 0.f};
#pragma unroll
    for (int k = 0; k < 4; ++k) {
        int t = lane + 64 * k;
        float v = row[2 * t];
        float ang = (PI2 / 256.0f) * (float)t;
        float s, c;
        sincosf(ang, &s, &c);
        float er = c, ei = -s;        // e^{-i*2pi*t/256}
        float pr = 1.f, pim = 0.f;    // (e^{-i ang})^kw, kw=0
#pragma unroll
        for (int kw = 0; kw < 4; ++kw) {
            ar[kw] += v * pr;
            ai[kw] += v * pim;
            float npr = pr * er - pim * ei;
            float npi = pr * ei + pim * er;
            pr = npr; pim = npi;
        }
    }
    // wave tree-reduce
#pragma unroll
    for (int m = 1; m < 64; m <<= 1) {
#pragma unroll
        for (int kw = 0; kw < 4; ++kw) {
            ar[kw] += __shfl_xor(ar[kw], m, 64);
            ai[kw] += __shfl_xor(ai[kw], m, 64);
        }
    }
    if (lane == 0) {
#pragma unroll
        for (int kw = 0; kw < 4; ++kw)
            partial[wid * 4 + kw] = make_float2(ar[kw], ai[kw]);
    }
}

// ---- K2: DFT over y (8 modes m in {0..3,-4..-1}). One WAVE per output. ----
__global__ void k_dft_y(const float2* __restrict__ partial, float2* __restrict__ FWc) {
    int gid  = blockIdx.x * blockDim.x + threadIdx.x;
    int wid  = gid >> 6;          // output idx in [0, 2048)
    int lane = gid & 63;
    int kw = wid & 3, midx = (wid >> 2) & 7, bc = wid >> 5;
    float m = (midx < 4) ? (float)midx : (float)(midx - 8);
    float2 acc = make_float2(0.f, 0.f);
#pragma unroll
    for (int k = 0; k < 4; ++k) {
        int y = lane + 64 * k;
        float2 p = partial[(bc * 256 + y) * 4 + kw];
        float ang = (PI2 / 256.0f) * m * (float)y;
        float s, c;
        sincosf(ang, &s, &c);
        // p * e^{-i ang} = p * (c - i s)
        acc.x += p.x * c + p.y * s;
        acc.y += p.y * c - p.x * s;
    }
#pragma unroll
    for (int msk = 1; msk < 64; msk <<= 1) {
        acc.x += __shfl_xor(acc.x, msk, 64);
        acc.y += __shfl_xor(acc.y, msk, 64);
    }
    if (lane == 0) FWc[wid] = acc;
}

// ---- K3: channel mix with weights. One thread per (b,o,midx,kw). ----
__global__ void k_mix(const float2* __restrict__ FWc, const float* __restrict__ w1,
                      const float* __restrict__ w2, float2* __restrict__ c2) {
    int tid = blockIdx.x * blockDim.x + threadIdx.x;  // 2048
    if (tid >= 2048) return;
    int kw = tid & 3, midx = (tid >> 2) & 7, o = (tid >> 5) & 7, b = tid >> 8;
    const float* w = (midx < 4) ? w1 : w2;
    int mx = midx & 3;
    float2 acc = make_float2(0.f, 0.f);
#pragma unroll
    for (int ci = 0; ci < 8; ++ci) {
        float2 f = FWc[((b * 8 + ci) * 8 + midx) * 4 + kw];
        const float* wp = w + ((((ci * 8 + o) * 4 + mx) * 4 + kw) * 2);
        float wr = wp[0], wi = wp[1];
        acc.x += f.x * wr - f.y * wi;
        acc.y += f.x * wi + f.y * wr;
    }
    c2[tid] = acc;
}

// ---- K4: h[b,o,z,kw] = sum_m c2 * e^{+2pi i m z/512}. One thread per output. ----
__global__ void k_h(const float2* __restrict__ c2, float2* __restrict__ h) {
    int tid = blockIdx.x * blockDim.x + threadIdx.x;  // 131072
    int kw = tid & 3, z = (tid >> 2) & 511, bo = tid >> 11;
    float2 acc = make_float2(0.f, 0.f);
#pragma unroll
    for (int midx = 0; midx < 8; ++midx) {
        float m = (midx < 4) ? (float)midx : (float)(midx - 8);
        float ang = (PI2 / 512.0f) * m * (float)z;
        float s, c;
        sincosf(ang, &s, &c);
        float2 cc = c2[(bo * 8 + midx) * 4 + kw];
        acc.x += cc.x * c - cc.y * s;
        acc.y += cc.x * s + cc.y * c;
    }
    h[tid] = acc;
}

// ---- K5: evaluate over i, write output. One wave per (b,o,z) row. ----
__global__ void k_eval(const float2* __restrict__ h, float* __restrict__ out) {
    int gid  = blockIdx.x * blockDim.x + threadIdx.x;
    int wid  = gid >> 6;          // row in [0, 32768)
    int lane = gid & 63;
    const float2* hr = h + (size_t)wid * 4;
    float2 h0 = hr[0], h1 = hr[1], h2 = hr[2], h3 = hr[3];
    float* orow = out + (size_t)wid * 512;
    const float inv = 1.0f / 65536.0f;
#pragma unroll
    for (int half = 0; half < 2; ++half) {
        int i0 = half * 256 + lane * 4;
        float4 r;
        float* rp = &r.x;
#pragma unroll
        for (int j = 0; j < 4; ++j) {
            int i = i0 + j;
            float ang = (PI2 / 512.0f) * (float)i;
            float s1, c1;
            sincosf(ang, &s1, &c1);
            float c2_ = c1 * c1 - s1 * s1, s2_ = 2.f * c1 * s1;
            float c3_ = c2_ * c1 - s2_ * s1, s3_ = s2_ * c1 + c2_ * s1;
            float v = h0.x
                    + h1.x * c1 - h1.y * s1
                    + h2.x * c2_ - h2.y * s2_
                    + h3.x * c3_ - h3.y * s3_;
            rp[j] = v * inv;
        }
        *(float4*)(orow + i0) = r;
    }
}

extern "C" void kernel_launch(void* const* d_in, const int* in_sizes, int n_in,
                              void* d_out, int out_size, void* d_ws, size_t ws_size,
                              hipStream_t stream) {
    const float* x  = (const float*)d_in[0];
    const float* w1 = (const float*)d_in[3];
    const float* w2 = (const float*)d_in[4];
    float* out = (float*)d_out;

    // workspace layout (float2 units)
    float2* partial = (float2*)d_ws;            // 64*256*4   = 65536
    float2* FWc     = partial + 65536;          // 64*8*4     = 2048
    float2* c2      = FWc + 2048;               // 64*8*4     = 2048
    float2* h       = c2 + 2048;                // 64*512*4   = 131072
    // total 201,728 float2 = ~1.6 MB

    // K1: 16384 waves = 1,048,576 threads
    k_dft_t<<<4096, 256, 0, stream>>>(x, partial);
    // K2: 2048 waves = 131072 threads
    k_dft_y<<<512, 256, 0, stream>>>(partial, FWc);
    // K3: 2048 threads
    k_mix<<<8, 256, 0, stream>>>(FWc, w1, w2, c2);
    // K4: 131072 threads
    k_h<<<512, 256, 0, stream>>>(c2, h);
    // K5: 32768 waves = 2,097,152 threads
    k_eval<<<8192, 256, 0, stream>>>(h, out);
}

// Round 3
// 33.455 us; speedup vs baseline: 2.9091x; 1.2574x over previous
//
#include <hip/hip_runtime.h>
#include <hip/hip_bf16.h>

// Problem: B=8, CIN=8, COUT=8, NX=NT=512, M1=M2=4.
// xs = x[:,:,::2,::2] (256x256); rfft2; keep modes (kx in {0..3,252..255}) x (kw in {0..3});
// mix over cin with w1 (rows 0..3) / w2 (rows 252..255); evaluate
// out[b,o,z,i] = Re( sum_{m,kw} c[b,o,m,kw] e^{2pi i (m z + kw i)/512} ) / 65536.

#define PI2 6.283185307179586f

// ---- K1: DFT over t (4 modes kw=0..3) per (b,cin,y) row. One wave per row.
// twiddle(t=lane+64k) = base(lane) * (-i)^k  -> only 1 sincosf per lane.
__global__ void k_dft_t(const float* __restrict__ x, float2* __restrict__ partial) {
    int gid  = blockIdx.x * blockDim.x + threadIdx.x;
    int wid  = gid >> 6;          // row index in [0, 64*256)
    int lane = gid & 63;
    int bc = wid >> 8;            // b*8+cin
    int y  = wid & 255;
    const float2* row2 = (const float2*)(x + ((size_t)bc * 512 + (size_t)(2 * y)) * 512);

    // base = e^{-2pi i lane/256}; powers p[kw] = base^kw
    float s, c;
    sincosf((PI2 / 256.0f) * (float)lane, &s, &c);
    float pr[4], pim[4];
    pr[0] = 1.f;                         pim[0] = 0.f;
    pr[1] = c;                           pim[1] = -s;
    pr[2] = pr[1]*pr[1] - pim[1]*pim[1]; pim[2] = 2.f*pr[1]*pim[1];
    pr[3] = pr[2]*pr[1] - pim[2]*pim[1]; pim[3] = pr[2]*pim[1] + pim[2]*pr[1];

    float ar[4] = {0.f,0.f,0.f,0.f};
    float ai[4] = {0.f,0.f,0.f,0.f};
#pragma unroll
    for (int k = 0; k < 4; ++k) {
        float v = row2[lane + 64 * k].x;     // x[.., 2t] with t=lane+64k
#pragma unroll
        for (int kw = 0; kw < 4; ++kw) {
            // e_t^kw = p[kw] * (-i)^{(k*kw)&3}
            int n = (k * kw) & 3;
            float rr, ri;
            if      (n == 0) { rr =  pr[kw]; ri =  pim[kw]; }
            else if (n == 1) { rr =  pim[kw]; ri = -pr[kw]; }
            else if (n == 2) { rr = -pr[kw]; ri = -pim[kw]; }
            else             { rr = -pim[kw]; ri =  pr[kw]; }
            ar[kw] += v * rr;
            ai[kw] += v * ri;
        }
    }
#pragma unroll
    for (int m = 1; m < 64; m <<= 1) {
#pragma unroll
        for (int kw = 0; kw < 4; ++kw) {
            ar[kw] += __shfl_xor(ar[kw], m, 64);
            ai[kw] += __shfl_xor(ai[kw], m, 64);
        }
    }
    if (lane == 0) {
#pragma unroll
        for (int kw = 0; kw < 4; ++kw)
            partial[wid * 4 + kw] = make_float2(ar[kw], ai[kw]);
    }
}

// ---- K23: fused y-DFT + channel mix. One wave per output (b,o,midx,kw).
// c2 = sum_y e^{-2pi i m y/256} * sum_ci w[ci]*partial[b,ci,y,kw]
__global__ void k_mix_y(const float2* __restrict__ partial, const float* __restrict__ w1,
                        const float* __restrict__ w2, float2* __restrict__ c2) {
    int gid  = blockIdx.x * blockDim.x + threadIdx.x;
    int wid  = gid >> 6;          // [0, 2048)
    int lane = gid & 63;
    int kw = wid & 3, midx = (wid >> 2) & 7, o = (wid >> 5) & 7, b = wid >> 8;
    float m = (midx < 4) ? (float)midx : (float)(midx - 8);
    const float* w = (midx < 4) ? w1 : w2;
    int mx = midx & 3;

    float wr[8], wi[8];           // wave-uniform -> scalar loads
#pragma unroll
    for (int ci = 0; ci < 8; ++ci) {
        const float* wp = w + ((((ci * 8 + o) * 4 + mx) * 4 + kw) * 2);
        wr[ci] = wp[0]; wi[ci] = wp[1];
    }

    float accx = 0.f, accy = 0.f;
#pragma unroll
    for (int k = 0; k < 4; ++k) {
        int y = lane + 64 * k;
        float sx = 0.f, sy = 0.f;
#pragma unroll
        for (int ci = 0; ci < 8; ++ci) {
            float2 p = partial[((b * 8 + ci) * 256 + y) * 4 + kw];
            sx += p.x * wr[ci] - p.y * wi[ci];
            sy += p.x * wi[ci] + p.y * wr[ci];
        }
        float ang = (PI2 / 256.0f) * m * (float)y;
        float s, c;
        sincosf(ang, &s, &c);
        accx += sx * c + sy * s;      // (sx+i sy) * (c - i s)
        accy += sy * c - sx * s;
    }
#pragma unroll
    for (int msk = 1; msk < 64; msk <<= 1) {
        accx += __shfl_xor(accx, msk, 64);
        accy += __shfl_xor(accy, msk, 64);
    }
    if (lane == 0) c2[wid] = make_float2(accx, accy);
}

// ---- K45: fused h + eval. One wave per (b,o,z) output row of 512.
__global__ void k_eval2(const float2* __restrict__ c2, float* __restrict__ out) {
    int gid  = blockIdx.x * blockDim.x + threadIdx.x;
    int wid  = gid >> 6;          // [0, 32768)
    int lane = gid & 63;
    int z  = wid & 511;
    int bo = wid >> 9;

    // lanes (ll=lane&31): midx=ll>>2, kw=ll&3; compute c2 * e^{2pi i m z/512}
    int ll = lane & 31;
    int kw = ll & 3, midx = (ll >> 2) & 7;
    float m = (midx < 4) ? (float)midx : (float)(midx - 8);
    float2 cc = c2[(bo * 8 + midx) * 4 + kw];
    float ang = (PI2 / 512.0f) * m * (float)z;
    float s, c;
    sincosf(ang, &s, &c);
    float hx = cc.x * c - cc.y * s;
    float hy = cc.x * s + cc.y * c;
    // reduce over midx (bits 2,3,4 of ll)
#pragma unroll
    for (int msk = 4; msk < 32; msk <<= 1) {
        hx += __shfl_xor(hx, msk, 64);
        hy += __shfl_xor(hy, msk, 64);
    }
    float h0x = __shfl(hx, 0, 64);
    float h1x = __shfl(hx, 1, 64), h1y = __shfl(hy, 1, 64);
    float h2x = __shfl(hx, 2, 64), h2y = __shfl(hy, 2, 64);
    float h3x = __shfl(hx, 3, 64), h3y = __shfl(hy, 3, 64);

    float* orow = out + (size_t)wid * 512;
    const float inv = 1.0f / 65536.0f;

    // theta_i = 2pi i/512, i = lane*4+j ; i+256 flips sign of odd-kw terms
    float c1, s1;
    sincosf((PI2 / 512.0f) * (float)(lane * 4), &s1, &c1);
    const float cr = 0.99992470183839f;     // cos(2pi/512)
    const float sr = 0.012271538285720f;    // sin(2pi/512)

    float4 r0, r1;
    float* rp0 = &r0.x;
    float* rp1 = &r1.x;
#pragma unroll
    for (int j = 0; j < 4; ++j) {
        float c2a = c1 * c1 - s1 * s1, s2a = 2.f * c1 * s1;
        float c3a = c2a * c1 - s2a * s1, s3a = s2a * c1 + c2a * s1;
        float t1 = h1x * c1  - h1y * s1;
        float t2 = h2x * c2a - h2y * s2a;
        float t3 = h3x * c3a - h3y * s3a;
        rp0[j] = (h0x + t1 + t2 + t3) * inv;
        rp1[j] = (h0x - t1 + t2 - t3) * inv;
        // rotate (c1,s1) by 2pi/512
        float nc = c1 * cr - s1 * sr;
        float ns = s1 * cr + c1 * sr;
        c1 = nc; s1 = ns;
    }
    *(float4*)(orow + lane * 4)       = r0;
    *(float4*)(orow + 256 + lane * 4) = r1;
}

extern "C" void kernel_launch(void* const* d_in, const int* in_sizes, int n_in,
                              void* d_out, int out_size, void* d_ws, size_t ws_size,
                              hipStream_t stream) {
    const float* x  = (const float*)d_in[0];
    const float* w1 = (const float*)d_in[3];
    const float* w2 = (const float*)d_in[4];
    float* out = (float*)d_out;

    float2* partial = (float2*)d_ws;            // 64*256*4 = 65536 float2 (512 KB)
    float2* c2      = partial + 65536;          // 64*8*4   = 2048  float2 (16 KB)

    // K1: 16384 waves
    k_dft_t<<<4096, 256, 0, stream>>>(x, partial);
    // K23: 2048 waves
    k_mix_y<<<512, 256, 0, stream>>>(partial, w1, w2, c2);
    // K45: 32768 waves
    k_eval2<<<8192, 256, 0, stream>>>(c2, out);
}

// Round 4
// 28.359 us; speedup vs baseline: 3.4318x; 1.1797x over previous
//
#include <hip/hip_runtime.h>
#include <hip/hip_bf16.h>

// Problem: B=8, CIN=8, COUT=8, NX=NT=512, M1=M2=4.
// out[b,o,z,i] = Re( sum_{m,kw} c2[b,o,m,kw] e^{2pi i (m z + kw i)/512} ) / 65536
// c2 = einsum over cin of rfft2(x[:,:,::2,::2]) low modes with w1/w2.
// partial2 layout: [b][kw][ci][y] float2  (transposed for dense K23 reads)

#define PI2 6.283185307179586f

// fold-reduce: after this, lanes with (lane&msk)==0 hold u summed over that
// lane bit; lanes with (lane&msk)!=0 hold v summed over that bit.
__device__ __forceinline__ float foldred(float u, float v, int msk, int lane) {
    float send = (lane & msk) ? u : v;
    float recv = __shfl_xor(send, msk, 64);
    return ((lane & msk) ? v : u) + recv;
}

// ---- K1: t-DFT (4 modes kw=0..3) per (b,cin,y) row. One wave per row.
__global__ void k_dft_t(const float* __restrict__ x, float* __restrict__ pf) {
    int gid  = blockIdx.x * blockDim.x + threadIdx.x;
    int wid  = gid >> 6;          // [0, 16384)
    int lane = gid & 63;
    int bc = wid >> 8;            // b*8+cin
    int y  = wid & 255;
    const float2* row2 = (const float2*)(x + ((size_t)bc * 512 + (size_t)(2 * y)) * 512);

    float v[4];
#pragma unroll
    for (int k = 0; k < 4; ++k) v[k] = row2[lane + 64 * k].x;   // x[..,2t], t=lane+64k

    // base = e^{-2pi i lane/256}; p[kw] = base^kw
    float s, c;
    sincosf((PI2 / 256.0f) * (float)lane, &s, &c);
    float pr[4], pim[4];
    pr[0] = 1.f;                         pim[0] = 0.f;
    pr[1] = c;                           pim[1] = -s;
    pr[2] = pr[1]*pr[1] - pim[1]*pim[1]; pim[2] = 2.f*pr[1]*pim[1];
    pr[3] = pr[2]*pr[1] - pim[2]*pim[1]; pim[3] = pr[2]*pim[1] + pim[2]*pr[1];

    float ar[4] = {0.f,0.f,0.f,0.f};
    float ai[4] = {0.f,0.f,0.f,0.f};
#pragma unroll
    for (int k = 0; k < 4; ++k) {
#pragma unroll
        for (int kw = 0; kw < 4; ++kw) {
            int n = (k * kw) & 3;          // twiddle = p[kw] * (-i)^n (compile-time n)
            float rr, ri;
            if      (n == 0) { rr =  pr[kw];  ri =  pim[kw]; }
            else if (n == 1) { rr =  pim[kw]; ri = -pr[kw];  }
            else if (n == 2) { rr = -pr[kw];  ri = -pim[kw]; }
            else             { rr = -pim[kw]; ri =  pr[kw];  }
            ar[kw] += v[k] * rr;
            ai[kw] += v[k] * ri;
        }
    }
    // fold 8 accumulators -> 1 register: lane&7 = kw*2 + (0:re,1:im)
    float A0 = foldred(ar[0], ai[0], 1, lane);
    float A1 = foldred(ar[1], ai[1], 1, lane);
    float A2 = foldred(ar[2], ai[2], 1, lane);
    float A3 = foldred(ar[3], ai[3], 1, lane);
    float B0 = foldred(A0, A1, 2, lane);
    float B1 = foldred(A2, A3, 2, lane);
    float C  = foldred(B0, B1, 4, lane);
    C += __shfl_xor(C, 8, 64);
    C += __shfl_xor(C, 16, 64);
    C += __shfl_xor(C, 32, 64);
    if (lane < 8) {
        int kw = lane >> 1, ri = lane & 1;
        int b = bc >> 3, ci = bc & 7;
        pf[(((size_t)(b * 4 + kw) * 8 + ci) * 256 + y) * 2 + ri] = C;
    }
}

// ---- K23: fused y-DFT + channel mix. One wave per (b,kw,midx,o); o fastest
// so the 4 waves of a block read identical partial lines (L1 hits).
__global__ void k_mix_y(const float2* __restrict__ partial2, const float* __restrict__ w1,
                        const float* __restrict__ w2, float* __restrict__ c2f) {
    int gid  = blockIdx.x * blockDim.x + threadIdx.x;
    int wid  = gid >> 6;          // [0, 2048)
    int lane = gid & 63;
    int o = wid & 7, midx = (wid >> 3) & 7, kw = (wid >> 6) & 3, b = wid >> 8;
    float m = (midx < 4) ? (float)midx : (float)(midx - 8);
    const float* w = (midx < 4) ? w1 : w2;
    int mx = midx & 3;

    float wr[8], wi[8];           // wave-uniform -> scalar loads
#pragma unroll
    for (int ci = 0; ci < 8; ++ci) {
        const float* wp = w + ((((ci * 8 + o) * 4 + mx) * 4 + kw) * 2);
        wr[ci] = wp[0]; wi[ci] = wp[1];
    }

    float accx = 0.f, accy = 0.f;
#pragma unroll
    for (int k = 0; k < 4; ++k) {
        int y = lane + 64 * k;
        float sx = 0.f, sy = 0.f;
#pragma unroll
        for (int ci = 0; ci < 8; ++ci) {
            float2 p = partial2[((b * 4 + kw) * 8 + ci) * 256 + y];  // dense in lane
            sx += p.x * wr[ci] - p.y * wi[ci];
            sy += p.x * wi[ci] + p.y * wr[ci];
        }
        float ang = (PI2 / 256.0f) * m * (float)y;
        float s, c;
        sincosf(ang, &s, &c);
        accx += sx * c + sy * s;      // (sx+i sy) * e^{-i ang}
        accy += sy * c - sx * s;
    }
    float A = foldred(accx, accy, 1, lane);   // lane&1: 0=re, 1=im
    A += __shfl_xor(A, 2, 64);
    A += __shfl_xor(A, 4, 64);
    A += __shfl_xor(A, 8, 64);
    A += __shfl_xor(A, 16, 64);
    A += __shfl_xor(A, 32, 64);
    if (lane < 2)
        c2f[(((b * 8 + o) * 8 + midx) * 4 + kw) * 2 + lane] = A;
}

// ---- K45: h + eval, two rows (z, z+256) per wave via h_m(z+256)=(-1)^midx h_m(z).
__global__ void k_eval2(const float2* __restrict__ c2, float* __restrict__ out) {
    int gid  = blockIdx.x * blockDim.x + threadIdx.x;
    int wid  = gid >> 6;          // [0, 16384)
    int lane = gid & 63;
    int z  = wid & 255;
    int bo = wid >> 8;

    int ll = lane & 31;
    int kw = ll & 3, midx = (ll >> 2) & 7;
    float m = (midx < 4) ? (float)midx : (float)(midx - 8);
    float2 cc = c2[(bo * 8 + midx) * 4 + kw];
    float ang = (PI2 / 512.0f) * m * (float)z;
    float s, c;
    sincosf(ang, &s, &c);
    float hx = cc.x * c - cc.y * s;
    float hy = cc.x * s + cc.y * c;
    float sg = (midx & 1) ? -1.f : 1.f;
    float gx = sg * hx, gy = sg * hy;

    // reduce over midx (ll bits 2,3,4); bit2 doubles as hx/hy selector
    float F = foldred(hx, hy, 4, lane);
    F += __shfl_xor(F, 8, 64);
    F += __shfl_xor(F, 16, 64);
    float G = foldred(gx, gy, 4, lane);
    G += __shfl_xor(G, 8, 64);
    G += __shfl_xor(G, 16, 64);
    // lane ll: ll<4 -> hx[kw=ll]; ll in 4..7 -> hy[kw=ll-4]
    float h0x = __shfl(F, 0, 64);
    float h1x = __shfl(F, 1, 64), h2x = __shfl(F, 2, 64), h3x = __shfl(F, 3, 64);
    float h1y = __shfl(F, 5, 64), h2y = __shfl(F, 6, 64), h3y = __shfl(F, 7, 64);
    float g0x = __shfl(G, 0, 64);
    float g1x = __shfl(G, 1, 64), g2x = __shfl(G, 2, 64), g3x = __shfl(G, 3, 64);
    float g1y = __shfl(G, 5, 64), g2y = __shfl(G, 6, 64), g3y = __shfl(G, 7, 64);

    float* orow0 = out + (size_t)(bo * 512 + z) * 512;
    float* orow1 = orow0 + 256 * 512;
    const float inv = 1.0f / 65536.0f;

    float c1, s1;
    sincosf((PI2 / 512.0f) * (float)(lane * 4), &s1, &c1);
    const float cr = 0.99992470183839f;     // cos(2pi/512)
    const float sr = 0.012271538285720f;    // sin(2pi/512)

    float4 r0, r1, q0, q1;
    float* rp0 = &r0.x; float* rp1 = &r1.x;
    float* qp0 = &q0.x; float* qp1 = &q1.x;
#pragma unroll
    for (int j = 0; j < 4; ++j) {
        float c2a = c1 * c1 - s1 * s1, s2a = 2.f * c1 * s1;
        float c3a = c2a * c1 - s2a * s1, s3a = s2a * c1 + c2a * s1;
        float t1 = h1x * c1  - h1y * s1;
        float t2 = h2x * c2a - h2y * s2a;
        float t3 = h3x * c3a - h3y * s3a;
        rp0[j] = (h0x + t1 + t2 + t3) * inv;
        rp1[j] = (h0x - t1 + t2 - t3) * inv;
        float u1 = g1x * c1  - g1y * s1;
        float u2 = g2x * c2a - g2y * s2a;
        float u3 = g3x * c3a - g3y * s3a;
        qp0[j] = (g0x + u1 + u2 + u3) * inv;
        qp1[j] = (g0x - u1 + u2 - u3) * inv;
        float nc = c1 * cr - s1 * sr;
        float ns = s1 * cr + c1 * sr;
        c1 = nc; s1 = ns;
    }
    *(float4*)(orow0 + lane * 4)       = r0;
    *(float4*)(orow0 + 256 + lane * 4) = r1;
    *(float4*)(orow1 + lane * 4)       = q0;
    *(float4*)(orow1 + 256 + lane * 4) = q1;
}

extern "C" void kernel_launch(void* const* d_in, const int* in_sizes, int n_in,
                              void* d_out, int out_size, void* d_ws, size_t ws_size,
                              hipStream_t stream) {
    const float* x  = (const float*)d_in[0];
    const float* w1 = (const float*)d_in[3];
    const float* w2 = (const float*)d_in[4];
    float* out = (float*)d_out;

    float* partial2 = (float*)d_ws;             // [8][4][8][256] float2 = 512 KB
    float* c2f      = partial2 + 131072;        // [8][8][8][4]   float2 = 16 KB

    k_dft_t<<<4096, 256, 0, stream>>>(x, partial2);
    k_mix_y<<<512, 256, 0, stream>>>((const float2*)partial2, w1, w2, c2f);
    k_eval2<<<4096, 256, 0, stream>>>((const float2*)c2f, out);
}